// Round 8
// baseline (327.274 us; speedup 1.0000x reference)
//
#include <hip/hip_runtime.h>
#include <stdint.h>
#include <math.h>

#define B_ 4
#define S_ 2048
#define D_ 4096
#define O_ 4096
#define E_ 8
#define R_ 32
#define SCALING 2.0f
#define NOISE_EPS 0.01f

typedef unsigned short u16;
typedef short s16x8 __attribute__((ext_vector_type(8)));   // 8 bf16 = 4 VGPRs
typedef float f32x4 __attribute__((ext_vector_type(4)));

__device__ __forceinline__ float b2f(u16 u) {
  union { unsigned int i; float f; } v; v.i = ((unsigned int)u) << 16; return v.f;
}
__device__ __forceinline__ u16 f2b(float f) {
  union { unsigned int i; float f; } v; v.f = f;
  unsigned int i = v.i;
  return (u16)((i + 0x7FFFu + ((i >> 16) & 1u)) >> 16);  // RNE
}
// two-term bf16 split: f = b2f(h) + b2f(l) + O(2^-17 |f|)
__device__ __forceinline__ void split2(float f, u16* h, u16* l) {
  u16 hi = f2b(f);
  *h = hi;
  *l = f2b(f - b2f(hi));   // f - b2f(hi) is exact in fp32
}

__device__ __forceinline__ float ld(const void* p, size_t i, int bf) {
  return bf ? b2f(((const u16*)p)[i]) : ((const float*)p)[i];
}

// Inline dtype probe: every wave reads the same first 64 words of x and
// ballots on "bits 14..7 look like a bf16 exponent". Uniform across waves
// and blocks -> no flag kernel, no cross-kernel dependency.
__device__ __forceinline__ int detect_bf(const unsigned int* __restrict__ xw) {
  unsigned int w = xw[threadIdx.x & 63];
  unsigned int e = (w >> 7) & 0xFFu;
  unsigned long long mask = __ballot((e >= 90u) && (e <= 140u));
  return (__popcll(mask) > 48) ? 1 : 0;
}

// ---------------------------------------------------------------------------
// Kernel 1 (fused prep): blocks [0,512) = Wc planes; blocks [512,576) = A
// planes (fp32 path only). Wc blocks compute the routing logits + noisy
// top-2 gates for their batch row INLINE (redundantly per block,
// deterministic, L2-hot) -- k_logits/k_gates kernels eliminated.
// Wc: Wp[b][ot][lane][8], ot=o>>4, lane=(r>>3)*16+(o&15), j=r&7.
// A : Ap[k32idx][half][lane][8], r=half*16+(lane&15), d=k32idx*32+(lane>>4)*8+j.
// ---------------------------------------------------------------------------
__global__ __launch_bounds__(256) void k_prep(
    const void* __restrict__ Bw, const float* __restrict__ Aw,
    const void* __restrict__ noise, const void* __restrict__ x,
    const int* __restrict__ eof,
    const void* __restrict__ route_w, const void* __restrict__ noise_w,
    u16* __restrict__ Wph, u16* __restrict__ Wpl,
    u16* __restrict__ Aph, u16* __restrict__ Apl) {
  int bf = detect_bf((const unsigned int*)x);
  int blk = blockIdx.x;
  int t = threadIdx.x;
  if (blk < 512) {
    int b = blk >> 7;                             // batch row (uniform)
    // --- inline logits: 8 e-groups x 32 threads, strided dot products
    __shared__ float lc[E_], ln_[E_];
    {
      int e = t >> 5, li = t & 31;
      size_t xoff = ((size_t)b * S_ + (size_t)eof[b]) * D_;
      size_t woff = (size_t)e * D_;
      float ac = 0.f, an = 0.f;
      for (int d = li; d < D_; d += 32) {
        float xv = ld(x, xoff + d, bf);
        ac += xv * ld(route_w, woff + d, bf);
        an += xv * ld(noise_w, woff + d, bf);
      }
#pragma unroll
      for (int off = 16; off > 0; off >>= 1) {
        ac += __shfl_xor(ac, off);
        an += __shfl_xor(an, off);
      }
      if (li == 0) { lc[e] = ac; ln_[e] = an; }
    }
    __syncthreads();
    // --- noisy top-2 gates (every thread, identical result)
    float lg[E_];
#pragma unroll
    for (int e = 0; e < E_; e++) {
      float n = ln_[e];
      float sp = (n > 20.f) ? n : log1pf(expf(n));
      lg[e] = lc[e] + ld(noise, b * 8 + e, bf) * (sp + NOISE_EPS);
    }
    int i1 = 0; float v1 = lg[0];
#pragma unroll
    for (int e = 1; e < E_; e++) if (lg[e] > v1) { v1 = lg[e]; i1 = e; }
    int i2 = -1; float v2 = -3.0e38f;
#pragma unroll
    for (int e = 0; e < E_; e++) if (e != i1 && lg[e] > v2) { v2 = lg[e]; i2 = e; }
    float tt = expf(v2 - v1);
    float g1 = 1.f / (1.f + tt);
    float g2 = tt / (1.f + tt);
    float g[E_];
#pragma unroll
    for (int e = 0; e < E_; e++) g[e] = 0.f;
    g[i1] = g1; g[i2] = g2;
    // --- Wc accumulation
    int idx = blk * 256 + t;                      // 0 .. 131071
    int u = idx & 32767;                          // o*8 + rq
    int o = u >> 3, rq = u & 7;
    f32x4 acc = {0.f, 0.f, 0.f, 0.f};
    if (bf) {
#pragma unroll
      for (int e = 0; e < E_; e++) {
        ushort4 v = ((const ushort4*)Bw)[(size_t)e * 32768 + u];
        acc[0] += g[e] * b2f(v.x);
        acc[1] += g[e] * b2f(v.y);
        acc[2] += g[e] * b2f(v.z);
        acc[3] += g[e] * b2f(v.w);
      }
    } else {
#pragma unroll
      for (int e = 0; e < E_; e++) {
        f32x4 v = ((const f32x4*)Bw)[(size_t)e * 32768 + u];
        acc += g[e] * v;
      }
    }
    acc *= SCALING;
    ushort4 h, l;
    split2(acc[0], &h.x, &l.x); split2(acc[1], &h.y, &l.y);
    split2(acc[2], &h.z, &l.z); split2(acc[3], &h.w, &l.w);
    int ot = o >> 4;
    int lane = ((rq >> 1) * 16) + (o & 15);
    size_t base = (((size_t)b * 256 + ot) * 64 + lane) * 8 + (rq & 1) * 4;
    *(ushort4*)(Wph + base) = h;
    *(ushort4*)(Wpl + base) = l;
  } else {
    if (bf) return;                               // bf16 inputs: A_w used directly
    int flat = (blk - 512) * 256 + t;             // 0 .. 16383
    int k32idx = flat >> 7;
    int rem = flat & 127;
    int hf = rem >> 6;
    int lane = rem & 63;
    int r = hf * 16 + (lane & 15);
    int d = k32idx * 32 + (lane >> 4) * 8;
    const float* src = Aw + (size_t)r * D_ + d;
    f32x4 v0 = *(const f32x4*)src;
    f32x4 v1 = *(const f32x4*)(src + 4);
    ushort4 h0, l0, h1, l1;
    split2(v0[0], &h0.x, &l0.x); split2(v0[1], &h0.y, &l0.y);
    split2(v0[2], &h0.z, &l0.z); split2(v0[3], &h0.w, &l0.w);
    split2(v1[0], &h1.x, &l1.x); split2(v1[1], &h1.y, &l1.y);
    split2(v1[2], &h1.z, &l1.z); split2(v1[3], &h1.w, &l1.w);
    *(ushort4*)(Aph + (size_t)flat * 8)     = h0;
    *(ushort4*)(Aph + (size_t)flat * 8 + 4) = h1;
    *(ushort4*)(Apl + (size_t)flat * 8)     = l0;
    *(ushort4*)(Apl + (size_t)flat * 8 + 4) = l1;
  }
}

// ---------------------------------------------------------------------------
// Kernel 2: partial shared projection via MFMA, D split 4 ways for occupancy.
// Block (rowgrp, dq) = 16 rows x 1024 k. Grid 2048 -> 8 blocks/CU.
// fp32 path: T14 issue-early/write-late pipeline -- chunk c+1's global loads
// are issued BEFORE chunk c's compute phase (held in 16 VGPRs), LDS write
// happens at the top of the next iteration. Same barrier count; HBM latency
// hides under ds_read+MFMA. XOR swizzle identical on write & read (rule 21).
// Output: fp32 partials, prepacked p[rowgrp][dq][lane][8].
// ---------------------------------------------------------------------------
__global__ __launch_bounds__(256) void k_sharedP(
    const void* __restrict__ xv, const void* __restrict__ Awv,
    const u16* __restrict__ Aph, const u16* __restrict__ Apl,
    float* __restrict__ pbuf) {
  __shared__ union {
    struct { u16 xh[4096]; u16 xl[4096]; } s;    // 16 KB staging
    float red4[4][512];                          // 8 KB reduce (after staging)
  } sm;
  int bf = detect_bf((const unsigned int*)xv);
  int t = threadIdx.x;
  int lane = t & 63;
  int wave = t >> 6;
  int m = lane & 15, kg = lane >> 4;
  int rowgrp = blockIdx.x >> 2;
  int dq = blockIdx.x & 3;
  int row0 = rowgrp * 16;
  f32x4 acc0 = {0.f, 0.f, 0.f, 0.f};
  f32x4 acc1 = {0.f, 0.f, 0.f, 0.f};
  if (bf) {
    // wave owns contiguous 256-k strip of this block's 1024-k range
    int kbase = dq * 1024 + wave * 256 + kg * 8;
    const u16* xp = (const u16*)xv + (size_t)(row0 + m) * D_ + kbase;
    const u16* a0 = (const u16*)Awv + (size_t)m * D_ + kbase;
    const u16* a1 = (const u16*)Awv + (size_t)(m + 16) * D_ + kbase;
#pragma unroll
    for (int k0 = 0; k0 < 256; k0 += 32) {
      s16x8 a  = *(const s16x8*)(xp + k0);
      s16x8 b0 = *(const s16x8*)(a0 + k0);
      s16x8 b1 = *(const s16x8*)(a1 + k0);
      acc0 = __builtin_amdgcn_mfma_f32_16x16x32_bf16(a, b0, acc0, 0, 0, 0);
      acc1 = __builtin_amdgcn_mfma_f32_16x16x32_bf16(a, b1, acc1, 0, 0, 0);
    }
  } else {
    int srow = t >> 4;                   // staging row 0..15
    int sq = t & 15;                     // staging quad 0..15
    const float* xrow = (const float*)xv + (size_t)(row0 + srow) * D_ + dq * 1024;
    f32x4 stg[4];
    // prologue: issue chunk 0 loads
#pragma unroll
    for (int q = 0; q < 4; q++)
      stg[q] = *(const f32x4*)(xrow + (sq + q * 16) * 4);
    for (int c = 0; c < 4; c++) {
      __syncthreads();                   // prior chunk's reads complete
      // write chunk c (in regs) to swizzled LDS
#pragma unroll
      for (int q = 0; q < 4; q++) {
        int colf = (sq + q * 16) * 4;    // float col within 256-chunk
        f32x4 v = stg[q];
        ushort4 h, l;
        split2(v[0], &h.x, &l.x); split2(v[1], &h.y, &l.y);
        split2(v[2], &h.z, &l.z); split2(v[3], &h.w, &l.w);
        int swz = (srow * 512 + colf * 2) ^ ((srow & 7) << 4);
        *(ushort4*)((char*)sm.s.xh + swz) = h;
        *(ushort4*)((char*)sm.s.xl + swz) = l;
      }
      // issue chunk c+1 loads NOW -- latency hides under compute below
      if (c < 3) {
#pragma unroll
        for (int q = 0; q < 4; q++)
          stg[q] = *(const f32x4*)(xrow + (c + 1) * 256 + (sq + q * 16) * 4);
      }
      __syncthreads();                   // staging visible to all waves
      // compute chunk c
#pragma unroll
      for (int p2 = 0; p2 < 2; p2++) {
        int k32 = (wave * 2 + p2) * 32;  // this wave's k sub-chunk in [0,256)
        int boff = (m * 512 + (k32 + kg * 8) * 2) ^ ((m & 7) << 4);
        s16x8 ah = *(const s16x8*)((const char*)sm.s.xh + boff);
        s16x8 al = *(const s16x8*)((const char*)sm.s.xl + boff);
        int k32idx = dq * 32 + c * 8 + wave * 2 + p2;
        const u16* ph = Aph + (size_t)k32idx * 1024;  // [half][lane][8]
        const u16* pl = Apl + (size_t)k32idx * 1024;
        s16x8 bh0 = *(const s16x8*)(ph + (size_t)lane * 8);
        s16x8 bl0 = *(const s16x8*)(pl + (size_t)lane * 8);
        s16x8 bh1 = *(const s16x8*)(ph + 512 + (size_t)lane * 8);
        s16x8 bl1 = *(const s16x8*)(pl + 512 + (size_t)lane * 8);
        acc0 = __builtin_amdgcn_mfma_f32_16x16x32_bf16(ah, bh0, acc0, 0, 0, 0);
        acc0 = __builtin_amdgcn_mfma_f32_16x16x32_bf16(ah, bl0, acc0, 0, 0, 0);
        acc0 = __builtin_amdgcn_mfma_f32_16x16x32_bf16(al, bh0, acc0, 0, 0, 0);
        acc1 = __builtin_amdgcn_mfma_f32_16x16x32_bf16(ah, bh1, acc1, 0, 0, 0);
        acc1 = __builtin_amdgcn_mfma_f32_16x16x32_bf16(ah, bl1, acc1, 0, 0, 0);
        acc1 = __builtin_amdgcn_mfma_f32_16x16x32_bf16(al, bh1, acc1, 0, 0, 0);
      }
    }
  }
  __syncthreads();                       // staging reads done before red reuse
  // deposit wave partials: C layout col(r)=lane&15, row=(lane>>4)*4+j
  int crow = (lane >> 4) * 4, ccol = lane & 15;
#pragma unroll
  for (int j = 0; j < 4; j++) {
    sm.red4[wave][(crow + j) * 32 + ccol]      = acc0[j];
    sm.red4[wave][(crow + j) * 32 + ccol + 16] = acc1[j];
  }
  __syncthreads();
  // one wave reduces 4 planes and stores fp32 partials prepacked:
  // thread t = rq*16 + row owns sh[row][rq*8 .. rq*8+7] -> dst = t*8 + j
  if (t < 64) {
    int row = t & 15, rq = t >> 4;
    f32x4 va, vb;
#pragma unroll
    for (int j = 0; j < 4; j++) {
      int e = row * 32 + rq * 8 + j;
      va[j] = sm.red4[0][e] + sm.red4[1][e] + sm.red4[2][e] + sm.red4[3][e];
    }
#pragma unroll
    for (int j = 0; j < 4; j++) {
      int e = row * 32 + rq * 8 + 4 + j;
      vb[j] = sm.red4[0][e] + sm.red4[1][e] + sm.red4[2][e] + sm.red4[3][e];
    }
    float* pp = pbuf + ((size_t)rowgrp * 4 + dq) * 512 + t * 8;
    *(f32x4*)pp = va;
    *(f32x4*)(pp + 4) = vb;
  }
}

// ---------------------------------------------------------------------------
// Kernel 3: out[row, o] = sum_r sh[row, r] * Wc[b, o, r] via MFMA.
// Block (rowgrp, oq) = 16 rows x 1024 o. Grid 2048 -> 8 blocks/CU.
// Sums 4 fp32 dq-partials in-register, splits to bf16 hi/lo fragments once,
// then 4 chunks of 256 o: 3-MFMA tiles -> LDS C [16][260] -> coalesced
// streaming stores (1 KB/wave-instr).
// ---------------------------------------------------------------------------
__global__ __launch_bounds__(256) void k_outP(
    const void* __restrict__ xv, const float* __restrict__ pbuf,
    const u16* __restrict__ Wph, const u16* __restrict__ Wpl,
    void* __restrict__ out) {
  __shared__ float C[16][260];
  int bf = detect_bf((const unsigned int*)xv);
  int t = threadIdx.x;
  int lane = t & 63, wave = t >> 6, m = lane & 15;
  int rowgrp = blockIdx.x >> 2;
  int oq = blockIdx.x & 3;
  int row0 = rowgrp * 16;
  int b = row0 >> 11;
  // reduce 4 dq-partials, build A fragments
  const float* pp = pbuf + (size_t)rowgrp * 4 * 512;
  f32x4 sa = {0.f, 0.f, 0.f, 0.f}, sb = {0.f, 0.f, 0.f, 0.f};
#pragma unroll
  for (int dq = 0; dq < 4; dq++) {
    sa += *(const f32x4*)(pp + dq * 512 + (size_t)lane * 8);
    sb += *(const f32x4*)(pp + dq * 512 + (size_t)lane * 8 + 4);
  }
  s16x8 Ah, Al;
  {
    u16 h, l;
#pragma unroll
    for (int j = 0; j < 4; j++) {
      split2(sa[j], &h, &l); Ah[j] = (short)h; Al[j] = (short)l;
      split2(sb[j], &h, &l); Ah[4 + j] = (short)h; Al[4 + j] = (short)l;
    }
  }
  int crow = (lane >> 4) * 4;
  const u16* whB = Wph + (size_t)b * 131072;   // 256 tiles * 512
  const u16* wlB = Wpl + (size_t)b * 131072;
  for (int cc = 0; cc < 4; cc++) {
    int tbase = oq * 64 + cc * 16;             // global tile base of chunk
#pragma unroll
    for (int i = 0; i < 4; i++) {
      int otc = wave * 4 + i;                  // tile within chunk 0..15
      size_t otg = (size_t)(tbase + otc);
      s16x8 Bh = *(const s16x8*)(whB + otg * 512 + (size_t)lane * 8);
      s16x8 Bl = *(const s16x8*)(wlB + otg * 512 + (size_t)lane * 8);
      f32x4 acc = {0.f, 0.f, 0.f, 0.f};
      acc = __builtin_amdgcn_mfma_f32_16x16x32_bf16(Ah, Bh, acc, 0, 0, 0);
      acc = __builtin_amdgcn_mfma_f32_16x16x32_bf16(Ah, Bl, acc, 0, 0, 0);
      acc = __builtin_amdgcn_mfma_f32_16x16x32_bf16(Al, Bh, acc, 0, 0, 0);
      int ocol = otc * 16 + m;
#pragma unroll
      for (int j = 0; j < 4; j++) C[crow + j][ocol] = acc[j];
    }
    __syncthreads();
    // stream 16 rows x 1 KB: 4 passes, 4 rows/pass, 1 KB contiguous/wave
#pragma unroll
    for (int pass = 0; pass < 4; pass++) {
      int row = pass * 4 + (t >> 6);
      int col = (t & 63) * 4;
      f32x4 v = *(const f32x4*)&C[row][col];
      size_t off = (size_t)(row0 + row) * O_ + oq * 1024 + cc * 256 + col;
      if (bf) {
        ushort4 o4;
        o4.x = f2b(v[0]); o4.y = f2b(v[1]); o4.z = f2b(v[2]); o4.w = f2b(v[3]);
        *(ushort4*)((u16*)out + off) = o4;
      } else {
        *(f32x4*)((float*)out + off) = v;
      }
    }
    __syncthreads();                           // C reuse next chunk
  }
}

// ---------------------------------------------------------------------------
extern "C" void kernel_launch(void* const* d_in, const int* in_sizes, int n_in,
                              void* d_out, int out_size, void* d_ws, size_t ws_size,
                              hipStream_t stream) {
  const void* x       = d_in[0];                 // [4,2048,4096] f32 or bf16
  const int*  eof     = (const int*)d_in[1];     // [4]
  const void* noise   = d_in[2];                 // [4,8]
  const void* Aw      = d_in[3];                 // [32,4096]
  const void* Bw      = d_in[4];                 // [8,4096,32]
  const void* route_w = d_in[5];                 // [8,4096]
  const void* noise_w = d_in[6];                 // [8,4096]
  float* wsf = (float*)d_ws;
  u16* Wph  = (u16*)(wsf + 112);                 // 524288 u16 = 1 MB
  u16* Wpl  = Wph + (size_t)B_ * O_ * R_;        // 1 MB
  u16* Aph  = Wpl + (size_t)B_ * O_ * R_;        // 256 KB
  u16* Apl  = Aph + (size_t)R_ * D_;             // 256 KB
  float* pbuf = (float*)(Apl + (size_t)R_ * D_); // 512*4*512 f32 = 4 MB

  k_prep<<<512 + 64, 256, 0, stream>>>(Bw, (const float*)Aw, noise, x, eof,
                                       route_w, noise_w, Wph, Wpl, Aph, Apl);
  k_sharedP<<<2048, 256, 0, stream>>>(x, Aw, Aph, Apl, pbuf);
  k_outP<<<2048, 256, 0, stream>>>(x, pbuf, Wph, Wpl, d_out);
}

// Round 9
// 285.935 us; speedup vs baseline: 1.1446x; 1.1446x over previous
//
#include <hip/hip_runtime.h>
#include <stdint.h>
#include <math.h>

#define B_ 4
#define S_ 2048
#define D_ 4096
#define O_ 4096
#define E_ 8
#define R_ 32
#define SCALING 2.0f
#define NOISE_EPS 0.01f

typedef unsigned short u16;
typedef short s16x8 __attribute__((ext_vector_type(8)));   // 8 bf16 = 4 VGPRs
typedef float f32x4 __attribute__((ext_vector_type(4)));

__device__ __forceinline__ float b2f(u16 u) {
  union { unsigned int i; float f; } v; v.i = ((unsigned int)u) << 16; return v.f;
}
__device__ __forceinline__ u16 f2b(float f) {
  union { unsigned int i; float f; } v; v.f = f;
  unsigned int i = v.i;
  return (u16)((i + 0x7FFFu + ((i >> 16) & 1u)) >> 16);  // RNE
}
// two-term bf16 split: f = b2f(h) + b2f(l) + O(2^-17 |f|)
__device__ __forceinline__ void split2(float f, u16* h, u16* l) {
  u16 hi = f2b(f);
  *h = hi;
  *l = f2b(f - b2f(hi));   // f - b2f(hi) is exact in fp32
}

__device__ __forceinline__ float ld(const void* p, size_t i, int bf) {
  return bf ? b2f(((const u16*)p)[i]) : ((const float*)p)[i];
}

// Inline dtype probe: every wave reads the same first 64 words of x and
// ballots on "bits 14..7 look like a bf16 exponent". Uniform across waves
// and blocks -> no flag kernel, no cross-kernel dependency.
__device__ __forceinline__ int detect_bf(const unsigned int* __restrict__ xw) {
  unsigned int w = xw[threadIdx.x & 63];
  unsigned int e = (w >> 7) & 0xFFu;
  unsigned long long mask = __ballot((e >= 90u) && (e <= 140u));
  return (__popcll(mask) > 48) ? 1 : 0;
}

// ---------------------------------------------------------------------------
// Kernel 1: clean/noise logits. One block per (b,e). Self-detects dtype.
// ---------------------------------------------------------------------------
__global__ __launch_bounds__(256) void k_logits(
    const void* __restrict__ x, const int* __restrict__ eof,
    const void* __restrict__ route_w, const void* __restrict__ noise_w,
    float* __restrict__ wsf) {
  int bf = detect_bf((const unsigned int*)x);
  int be = blockIdx.x;            // 0..31
  int b = be >> 3, e = be & 7;
  size_t xoff = ((size_t)b * S_ + (size_t)eof[b]) * D_;
  size_t woff = (size_t)e * D_;
  float ac = 0.f, an = 0.f;
  for (int d = threadIdx.x; d < D_; d += 256) {
    float xv = ld(x, xoff + d, bf);
    ac += xv * ld(route_w, woff + d, bf);
    an += xv * ld(noise_w, woff + d, bf);
  }
  __shared__ float rc[256], rn[256];
  rc[threadIdx.x] = ac; rn[threadIdx.x] = an;
  __syncthreads();
  for (int s = 128; s > 0; s >>= 1) {
    if (threadIdx.x < (unsigned)s) {
      rc[threadIdx.x] += rc[threadIdx.x + s];
      rn[threadIdx.x] += rn[threadIdx.x + s];
    }
    __syncthreads();
  }
  if (threadIdx.x == 0) { wsf[16 + be] = rc[0]; wsf[48 + be] = rn[0]; }
}

// ---------------------------------------------------------------------------
// Kernel 2 (fused prep): blocks [0,512) = Wc planes (gates recomputed
// per-thread from staged logits -- k_gates kernel eliminated); blocks
// [512,576) = A planes (fp32 path only). PREPACKED fragment-order bf16 hi/lo.
// Wc: Wp[b][ot][lane][8], ot=o>>4, lane=(r>>3)*16+(o&15), j=r&7.
// A : Ap[k32idx][half][lane][8], r=half*16+(lane&15), d=k32idx*32+(lane>>4)*8+j.
// ---------------------------------------------------------------------------
__global__ __launch_bounds__(256) void k_prep(
    const void* __restrict__ Bw, const float* __restrict__ Aw,
    const void* __restrict__ noise, const void* __restrict__ x,
    const float* __restrict__ wsf,
    u16* __restrict__ Wph, u16* __restrict__ Wpl,
    u16* __restrict__ Aph, u16* __restrict__ Apl) {
  int bf = detect_bf((const unsigned int*)x);
  int blk = blockIdx.x;
  if (blk < 512) {
    int idx = blk * 256 + threadIdx.x;            // 0 .. 131071
    int b = idx >> 15;                            // uniform per block
    // --- noisy top-2 gates, recomputed redundantly (cheap, removes launch)
    float lg[E_];
#pragma unroll
    for (int e = 0; e < E_; e++) {
      float c = wsf[16 + b * 8 + e];
      float n = wsf[48 + b * 8 + e];
      float sp = (n > 20.f) ? n : log1pf(expf(n));
      lg[e] = c + ld(noise, b * 8 + e, bf) * (sp + NOISE_EPS);
    }
    int i1 = 0; float v1 = lg[0];
#pragma unroll
    for (int e = 1; e < E_; e++) if (lg[e] > v1) { v1 = lg[e]; i1 = e; }
    int i2 = -1; float v2 = -3.0e38f;
#pragma unroll
    for (int e = 0; e < E_; e++) if (e != i1 && lg[e] > v2) { v2 = lg[e]; i2 = e; }
    float tt = expf(v2 - v1);
    float g1 = 1.f / (1.f + tt);
    float g2 = tt / (1.f + tt);
    float g[E_];
#pragma unroll
    for (int e = 0; e < E_; e++) g[e] = 0.f;
    g[i1] = g1; g[i2] = g2;
    // --- Wc accumulation
    int u = idx & 32767;                          // o*8 + rq
    int o = u >> 3, rq = u & 7;
    f32x4 acc = {0.f, 0.f, 0.f, 0.f};
    if (bf) {
#pragma unroll
      for (int e = 0; e < E_; e++) {
        ushort4 v = ((const ushort4*)Bw)[(size_t)e * 32768 + u];
        acc[0] += g[e] * b2f(v.x);
        acc[1] += g[e] * b2f(v.y);
        acc[2] += g[e] * b2f(v.z);
        acc[3] += g[e] * b2f(v.w);
      }
    } else {
#pragma unroll
      for (int e = 0; e < E_; e++) {
        f32x4 v = ((const f32x4*)Bw)[(size_t)e * 32768 + u];
        acc += g[e] * v;
      }
    }
    acc *= SCALING;
    ushort4 h, l;
    split2(acc[0], &h.x, &l.x); split2(acc[1], &h.y, &l.y);
    split2(acc[2], &h.z, &l.z); split2(acc[3], &h.w, &l.w);
    int ot = o >> 4;
    int lane = ((rq >> 1) * 16) + (o & 15);
    size_t base = (((size_t)b * 256 + ot) * 64 + lane) * 8 + (rq & 1) * 4;
    *(ushort4*)(Wph + base) = h;
    *(ushort4*)(Wpl + base) = l;
  } else {
    if (bf) return;                               // bf16 inputs: A_w used directly
    int flat = (blk - 512) * 256 + threadIdx.x;   // 0 .. 16383
    int k32idx = flat >> 7;
    int rem = flat & 127;
    int hf = rem >> 6;
    int lane = rem & 63;
    int r = hf * 16 + (lane & 15);
    int d = k32idx * 32 + (lane >> 4) * 8;
    const float* src = Aw + (size_t)r * D_ + d;
    f32x4 v0 = *(const f32x4*)src;
    f32x4 v1 = *(const f32x4*)(src + 4);
    ushort4 h0, l0, h1, l1;
    split2(v0[0], &h0.x, &l0.x); split2(v0[1], &h0.y, &l0.y);
    split2(v0[2], &h0.z, &l0.z); split2(v0[3], &h0.w, &l0.w);
    split2(v1[0], &h1.x, &l1.x); split2(v1[1], &h1.y, &l1.y);
    split2(v1[2], &h1.z, &l1.z); split2(v1[3], &h1.w, &l1.w);
    *(ushort4*)(Aph + (size_t)flat * 8)     = h0;
    *(ushort4*)(Aph + (size_t)flat * 8 + 4) = h1;
    *(ushort4*)(Apl + (size_t)flat * 8)     = l0;
    *(ushort4*)(Apl + (size_t)flat * 8 + 4) = l1;
  }
}

// ---------------------------------------------------------------------------
// Kernel 3: partial shared projection via MFMA, D split 4 ways for occupancy.
// Block (rowgrp, dq) = 16 rows x 1024 k. Grid 2048 -> 8 blocks/CU.
// fp32 path: x staged+split to swizzled LDS (4 chunks of 256 k, short
// barrier chain); bf16 path: direct fragment loads.
// Output: fp32 partials, prepacked fragment order p[rowgrp][dq][lane][8]
// (lane = (r>>3)*16 + row, j = r&7) -- consumer sums 4 dq and splits.
// ---------------------------------------------------------------------------
__global__ __launch_bounds__(256) void k_sharedP(
    const void* __restrict__ xv, const void* __restrict__ Awv,
    const u16* __restrict__ Aph, const u16* __restrict__ Apl,
    float* __restrict__ pbuf) {
  __shared__ union {
    struct { u16 xh[4096]; u16 xl[4096]; } s;    // 16 KB staging
    float red4[4][512];                          // 8 KB reduce (after staging)
  } sm;
  int bf = detect_bf((const unsigned int*)xv);
  int t = threadIdx.x;
  int lane = t & 63;
  int wave = t >> 6;
  int m = lane & 15, kg = lane >> 4;
  int rowgrp = blockIdx.x >> 2;
  int dq = blockIdx.x & 3;
  int row0 = rowgrp * 16;
  f32x4 acc0 = {0.f, 0.f, 0.f, 0.f};
  f32x4 acc1 = {0.f, 0.f, 0.f, 0.f};
  if (bf) {
    // wave owns contiguous 256-k strip of this block's 1024-k range
    int kbase = dq * 1024 + wave * 256 + kg * 8;
    const u16* xp = (const u16*)xv + (size_t)(row0 + m) * D_ + kbase;
    const u16* a0 = (const u16*)Awv + (size_t)m * D_ + kbase;
    const u16* a1 = (const u16*)Awv + (size_t)(m + 16) * D_ + kbase;
#pragma unroll
    for (int k0 = 0; k0 < 256; k0 += 32) {
      s16x8 a  = *(const s16x8*)(xp + k0);
      s16x8 b0 = *(const s16x8*)(a0 + k0);
      s16x8 b1 = *(const s16x8*)(a1 + k0);
      acc0 = __builtin_amdgcn_mfma_f32_16x16x32_bf16(a, b0, acc0, 0, 0, 0);
      acc1 = __builtin_amdgcn_mfma_f32_16x16x32_bf16(a, b1, acc1, 0, 0, 0);
    }
  } else {
    int srow = t >> 4;                   // staging row 0..15
    int sq = t & 15;                     // staging quad 0..15
    const float* xrow = (const float*)xv + (size_t)(row0 + srow) * D_ + dq * 1024;
    for (int c = 0; c < 4; c++) {
      __syncthreads();                   // protect previous iter's reads
#pragma unroll
      for (int q = 0; q < 4; q++) {
        int colf = (sq + q * 16) * 4;    // float col within 256-chunk
        f32x4 v = *(const f32x4*)(xrow + c * 256 + colf);
        ushort4 h, l;
        split2(v[0], &h.x, &l.x); split2(v[1], &h.y, &l.y);
        split2(v[2], &h.z, &l.z); split2(v[3], &h.w, &l.w);
        // XOR on FULL byte address; identical formula on read side (rule 21)
        int swz = (srow * 512 + colf * 2) ^ ((srow & 7) << 4);
        *(ushort4*)((char*)sm.s.xh + swz) = h;
        *(ushort4*)((char*)sm.s.xl + swz) = l;
      }
      __syncthreads();
#pragma unroll
      for (int p2 = 0; p2 < 2; p2++) {
        int k32 = (wave * 2 + p2) * 32;  // this wave's k sub-chunk in [0,256)
        int boff = (m * 512 + (k32 + kg * 8) * 2) ^ ((m & 7) << 4);
        s16x8 ah = *(const s16x8*)((const char*)sm.s.xh + boff);
        s16x8 al = *(const s16x8*)((const char*)sm.s.xl + boff);
        int k32idx = dq * 32 + c * 8 + wave * 2 + p2;
        const u16* ph = Aph + (size_t)k32idx * 1024;  // [half][lane][8]
        const u16* pl = Apl + (size_t)k32idx * 1024;
        s16x8 bh0 = *(const s16x8*)(ph + (size_t)lane * 8);
        s16x8 bl0 = *(const s16x8*)(pl + (size_t)lane * 8);
        s16x8 bh1 = *(const s16x8*)(ph + 512 + (size_t)lane * 8);
        s16x8 bl1 = *(const s16x8*)(pl + 512 + (size_t)lane * 8);
        acc0 = __builtin_amdgcn_mfma_f32_16x16x32_bf16(ah, bh0, acc0, 0, 0, 0);
        acc0 = __builtin_amdgcn_mfma_f32_16x16x32_bf16(ah, bl0, acc0, 0, 0, 0);
        acc0 = __builtin_amdgcn_mfma_f32_16x16x32_bf16(al, bh0, acc0, 0, 0, 0);
        acc1 = __builtin_amdgcn_mfma_f32_16x16x32_bf16(ah, bh1, acc1, 0, 0, 0);
        acc1 = __builtin_amdgcn_mfma_f32_16x16x32_bf16(ah, bl1, acc1, 0, 0, 0);
        acc1 = __builtin_amdgcn_mfma_f32_16x16x32_bf16(al, bh1, acc1, 0, 0, 0);
      }
    }
  }
  __syncthreads();                       // staging reads done before red reuse
  // deposit wave partials: C layout col(r)=lane&15, row=(lane>>4)*4+j
  int crow = (lane >> 4) * 4, ccol = lane & 15;
#pragma unroll
  for (int j = 0; j < 4; j++) {
    sm.red4[wave][(crow + j) * 32 + ccol]      = acc0[j];
    sm.red4[wave][(crow + j) * 32 + ccol + 16] = acc1[j];
  }
  __syncthreads();
  // one wave reduces 4 planes and stores fp32 partials prepacked:
  // thread t = rq*16 + row owns sh[row][rq*8 .. rq*8+7] -> dst = t*8 + j
  if (t < 64) {
    int row = t & 15, rq = t >> 4;
    f32x4 va, vb;
#pragma unroll
    for (int j = 0; j < 4; j++) {
      int e = row * 32 + rq * 8 + j;
      va[j] = sm.red4[0][e] + sm.red4[1][e] + sm.red4[2][e] + sm.red4[3][e];
    }
#pragma unroll
    for (int j = 0; j < 4; j++) {
      int e = row * 32 + rq * 8 + 4 + j;
      vb[j] = sm.red4[0][e] + sm.red4[1][e] + sm.red4[2][e] + sm.red4[3][e];
    }
    float* pp = pbuf + ((size_t)rowgrp * 4 + dq) * 512 + t * 8;
    *(f32x4*)pp = va;
    *(f32x4*)(pp + 4) = vb;
  }
}

// ---------------------------------------------------------------------------
// Kernel 4: out[row, o] = sum_r sh[row, r] * Wc[b, o, r] via MFMA.
// Block (rowgrp, oq) = 16 rows x 1024 o. Grid 2048 -> 8 blocks/CU.
// Sums 4 fp32 dq-partials in-register (coalesced 32B/lane), splits to bf16
// hi/lo fragments once, then 4 chunks of 256 o: 3-MFMA tiles -> LDS C
// [16][260] -> coalesced streaming stores (1 KB/wave-instr).
// ---------------------------------------------------------------------------
__global__ __launch_bounds__(256) void k_outP(
    const void* __restrict__ xv, const float* __restrict__ pbuf,
    const u16* __restrict__ Wph, const u16* __restrict__ Wpl,
    void* __restrict__ out) {
  __shared__ float C[16][260];
  int bf = detect_bf((const unsigned int*)xv);
  int t = threadIdx.x;
  int lane = t & 63, wave = t >> 6, m = lane & 15;
  int rowgrp = blockIdx.x >> 2;
  int oq = blockIdx.x & 3;
  int row0 = rowgrp * 16;
  int b = row0 >> 11;
  // reduce 4 dq-partials, build A fragments
  const float* pp = pbuf + (size_t)rowgrp * 4 * 512;
  f32x4 sa = {0.f, 0.f, 0.f, 0.f}, sb = {0.f, 0.f, 0.f, 0.f};
#pragma unroll
  for (int dq = 0; dq < 4; dq++) {
    sa += *(const f32x4*)(pp + dq * 512 + (size_t)lane * 8);
    sb += *(const f32x4*)(pp + dq * 512 + (size_t)lane * 8 + 4);
  }
  s16x8 Ah, Al;
  {
    u16 h, l;
#pragma unroll
    for (int j = 0; j < 4; j++) {
      split2(sa[j], &h, &l); Ah[j] = (short)h; Al[j] = (short)l;
      split2(sb[j], &h, &l); Ah[4 + j] = (short)h; Al[4 + j] = (short)l;
    }
  }
  int crow = (lane >> 4) * 4;
  const u16* whB = Wph + (size_t)b * 131072;   // 256 tiles * 512
  const u16* wlB = Wpl + (size_t)b * 131072;
  for (int cc = 0; cc < 4; cc++) {
    int tbase = oq * 64 + cc * 16;             // global tile base of chunk
#pragma unroll
    for (int i = 0; i < 4; i++) {
      int otc = wave * 4 + i;                  // tile within chunk 0..15
      size_t otg = (size_t)(tbase + otc);
      s16x8 Bh = *(const s16x8*)(whB + otg * 512 + (size_t)lane * 8);
      s16x8 Bl = *(const s16x8*)(wlB + otg * 512 + (size_t)lane * 8);
      f32x4 acc = {0.f, 0.f, 0.f, 0.f};
      acc = __builtin_amdgcn_mfma_f32_16x16x32_bf16(Ah, Bh, acc, 0, 0, 0);
      acc = __builtin_amdgcn_mfma_f32_16x16x32_bf16(Ah, Bl, acc, 0, 0, 0);
      acc = __builtin_amdgcn_mfma_f32_16x16x32_bf16(Al, Bh, acc, 0, 0, 0);
      int ocol = otc * 16 + m;
#pragma unroll
      for (int j = 0; j < 4; j++) C[crow + j][ocol] = acc[j];
    }
    __syncthreads();
    // stream 16 rows x 1 KB: 4 passes, 4 rows/pass, 1 KB contiguous/wave
#pragma unroll
    for (int pass = 0; pass < 4; pass++) {
      int row = pass * 4 + (t >> 6);
      int col = (t & 63) * 4;
      f32x4 v = *(const f32x4*)&C[row][col];
      size_t off = (size_t)(row0 + row) * O_ + oq * 1024 + cc * 256 + col;
      if (bf) {
        ushort4 o4;
        o4.x = f2b(v[0]); o4.y = f2b(v[1]); o4.z = f2b(v[2]); o4.w = f2b(v[3]);
        *(ushort4*)((u16*)out + off) = o4;
      } else {
        *(f32x4*)((float*)out + off) = v;
      }
    }
    __syncthreads();                           // C reuse next chunk
  }
}

// ---------------------------------------------------------------------------
extern "C" void kernel_launch(void* const* d_in, const int* in_sizes, int n_in,
                              void* d_out, int out_size, void* d_ws, size_t ws_size,
                              hipStream_t stream) {
  const void* x       = d_in[0];                 // [4,2048,4096] f32 or bf16
  const int*  eof     = (const int*)d_in[1];     // [4]
  const void* noise   = d_in[2];                 // [4,8]
  const void* Aw      = d_in[3];                 // [32,4096]
  const void* Bw      = d_in[4];                 // [8,4096,32]
  const void* route_w = d_in[5];                 // [8,4096]
  const void* noise_w = d_in[6];                 // [8,4096]
  float* wsf = (float*)d_ws;
  // ws layout: [16,48) clean logits | [48,80) noise logits | then u16 planes
  u16* Wph  = (u16*)(wsf + 112);                 // 524288 u16 = 1 MB
  u16* Wpl  = Wph + (size_t)B_ * O_ * R_;        // 1 MB
  u16* Aph  = Wpl + (size_t)B_ * O_ * R_;        // 256 KB
  u16* Apl  = Aph + (size_t)R_ * D_;             // 256 KB
  float* pbuf = (float*)(Apl + (size_t)R_ * D_); // 512*4*512 f32 = 4 MB

  k_logits<<<B_ * E_, 256, 0, stream>>>(x, eof, route_w, noise_w, wsf);
  k_prep<<<512 + 64, 256, 0, stream>>>(Bw, (const float*)Aw, noise, x, wsf,
                                       Wph, Wpl, Aph, Apl);
  k_sharedP<<<2048, 256, 0, stream>>>(x, Aw, Aph, Apl, pbuf);
  k_outP<<<2048, 256, 0, stream>>>(x, pbuf, Wph, Wpl, d_out);
}

// Round 10
// 274.488 us; speedup vs baseline: 1.1923x; 1.0417x over previous
//
#include <hip/hip_runtime.h>
#include <stdint.h>
#include <math.h>

#define B_ 4
#define S_ 2048
#define D_ 4096
#define O_ 4096
#define E_ 8
#define R_ 32
#define SCALING 2.0f
#define NOISE_EPS 0.01f

typedef unsigned short u16;
typedef short s16x8 __attribute__((ext_vector_type(8)));   // 8 bf16 = 4 VGPRs
typedef float f32x4 __attribute__((ext_vector_type(4)));

__device__ __forceinline__ float b2f(u16 u) {
  union { unsigned int i; float f; } v; v.i = ((unsigned int)u) << 16; return v.f;
}
__device__ __forceinline__ u16 f2b(float f) {
  union { unsigned int i; float f; } v; v.f = f;
  unsigned int i = v.i;
  return (u16)((i + 0x7FFFu + ((i >> 16) & 1u)) >> 16);  // RNE
}
// two-term bf16 split: f = b2f(h) + b2f(l) + O(2^-17 |f|)
__device__ __forceinline__ void split2(float f, u16* h, u16* l) {
  u16 hi = f2b(f);
  *h = hi;
  *l = f2b(f - b2f(hi));   // f - b2f(hi) is exact in fp32
}

__device__ __forceinline__ float ld(const void* p, size_t i, int bf) {
  return bf ? b2f(((const u16*)p)[i]) : ((const float*)p)[i];
}

// Inline dtype probe: every wave reads the same first 64 words of x and
// ballots on "bits 14..7 look like a bf16 exponent". Uniform across waves
// and blocks -> no flag kernel, no cross-kernel dependency.
__device__ __forceinline__ int detect_bf(const unsigned int* __restrict__ xw) {
  unsigned int w = xw[threadIdx.x & 63];
  unsigned int e = (w >> 7) & 0xFFu;
  unsigned long long mask = __ballot((e >= 90u) && (e <= 140u));
  return (__popcll(mask) > 48) ? 1 : 0;
}

// ---------------------------------------------------------------------------
// Kernel 1: clean/noise logits. One block per (b,e). Self-detects dtype.
// ---------------------------------------------------------------------------
__global__ __launch_bounds__(256) void k_logits(
    const void* __restrict__ x, const int* __restrict__ eof,
    const void* __restrict__ route_w, const void* __restrict__ noise_w,
    float* __restrict__ wsf) {
  int bf = detect_bf((const unsigned int*)x);
  int be = blockIdx.x;            // 0..31
  int b = be >> 3, e = be & 7;
  size_t xoff = ((size_t)b * S_ + (size_t)eof[b]) * D_;
  size_t woff = (size_t)e * D_;
  float ac = 0.f, an = 0.f;
  for (int d = threadIdx.x; d < D_; d += 256) {
    float xv = ld(x, xoff + d, bf);
    ac += xv * ld(route_w, woff + d, bf);
    an += xv * ld(noise_w, woff + d, bf);
  }
  __shared__ float rc[256], rn[256];
  rc[threadIdx.x] = ac; rn[threadIdx.x] = an;
  __syncthreads();
  for (int s = 128; s > 0; s >>= 1) {
    if (threadIdx.x < (unsigned)s) {
      rc[threadIdx.x] += rc[threadIdx.x + s];
      rn[threadIdx.x] += rn[threadIdx.x + s];
    }
    __syncthreads();
  }
  if (threadIdx.x == 0) { wsf[16 + be] = rc[0]; wsf[48 + be] = rn[0]; }
}

// ---------------------------------------------------------------------------
// Kernel 2 (fused prep): blocks [0,512) = Wc planes (gates recomputed
// per-thread from staged logits); blocks [512,576) = A planes (fp32 path
// only). PREPACKED fragment-order bf16 hi/lo.
// Wc: Wp[b][ot][lane][8], ot=o>>4, lane=(r>>3)*16+(o&15), j=r&7.
// A : Ap[k32idx][half][lane][8], r=half*16+(lane&15), d=k32idx*32+(lane>>4)*8+j.
// ---------------------------------------------------------------------------
__global__ __launch_bounds__(256) void k_prep(
    const void* __restrict__ Bw, const float* __restrict__ Aw,
    const void* __restrict__ noise, const void* __restrict__ x,
    const float* __restrict__ wsf,
    u16* __restrict__ Wph, u16* __restrict__ Wpl,
    u16* __restrict__ Aph, u16* __restrict__ Apl) {
  int bf = detect_bf((const unsigned int*)x);
  int blk = blockIdx.x;
  if (blk < 512) {
    int idx = blk * 256 + threadIdx.x;            // 0 .. 131071
    int b = idx >> 15;                            // uniform per block
    // --- noisy top-2 gates, recomputed redundantly (cheap, removes launch)
    float lg[E_];
#pragma unroll
    for (int e = 0; e < E_; e++) {
      float c = wsf[16 + b * 8 + e];
      float n = wsf[48 + b * 8 + e];
      float sp = (n > 20.f) ? n : log1pf(expf(n));
      lg[e] = c + ld(noise, b * 8 + e, bf) * (sp + NOISE_EPS);
    }
    int i1 = 0; float v1 = lg[0];
#pragma unroll
    for (int e = 1; e < E_; e++) if (lg[e] > v1) { v1 = lg[e]; i1 = e; }
    int i2 = -1; float v2 = -3.0e38f;
#pragma unroll
    for (int e = 0; e < E_; e++) if (e != i1 && lg[e] > v2) { v2 = lg[e]; i2 = e; }
    float tt = expf(v2 - v1);
    float g1 = 1.f / (1.f + tt);
    float g2 = tt / (1.f + tt);
    float g[E_];
#pragma unroll
    for (int e = 0; e < E_; e++) g[e] = 0.f;
    g[i1] = g1; g[i2] = g2;
    // --- Wc accumulation
    int u = idx & 32767;                          // o*8 + rq
    int o = u >> 3, rq = u & 7;
    f32x4 acc = {0.f, 0.f, 0.f, 0.f};
    if (bf) {
#pragma unroll
      for (int e = 0; e < E_; e++) {
        ushort4 v = ((const ushort4*)Bw)[(size_t)e * 32768 + u];
        acc[0] += g[e] * b2f(v.x);
        acc[1] += g[e] * b2f(v.y);
        acc[2] += g[e] * b2f(v.z);
        acc[3] += g[e] * b2f(v.w);
      }
    } else {
#pragma unroll
      for (int e = 0; e < E_; e++) {
        f32x4 v = ((const f32x4*)Bw)[(size_t)e * 32768 + u];
        acc += g[e] * v;
      }
    }
    acc *= SCALING;
    ushort4 h, l;
    split2(acc[0], &h.x, &l.x); split2(acc[1], &h.y, &l.y);
    split2(acc[2], &h.z, &l.z); split2(acc[3], &h.w, &l.w);
    int ot = o >> 4;
    int lane = ((rq >> 1) * 16) + (o & 15);
    size_t base = (((size_t)b * 256 + ot) * 64 + lane) * 8 + (rq & 1) * 4;
    *(ushort4*)(Wph + base) = h;
    *(ushort4*)(Wpl + base) = l;
  } else {
    if (bf) return;                               // bf16 inputs: A_w used directly
    int flat = (blk - 512) * 256 + threadIdx.x;   // 0 .. 16383
    int k32idx = flat >> 7;
    int rem = flat & 127;
    int hf = rem >> 6;
    int lane = rem & 63;
    int r = hf * 16 + (lane & 15);
    int d = k32idx * 32 + (lane >> 4) * 8;
    const float* src = Aw + (size_t)r * D_ + d;
    f32x4 v0 = *(const f32x4*)src;
    f32x4 v1 = *(const f32x4*)(src + 4);
    ushort4 h0, l0, h1, l1;
    split2(v0[0], &h0.x, &l0.x); split2(v0[1], &h0.y, &l0.y);
    split2(v0[2], &h0.z, &l0.z); split2(v0[3], &h0.w, &l0.w);
    split2(v1[0], &h1.x, &l1.x); split2(v1[1], &h1.y, &l1.y);
    split2(v1[2], &h1.z, &l1.z); split2(v1[3], &h1.w, &l1.w);
    *(ushort4*)(Aph + (size_t)flat * 8)     = h0;
    *(ushort4*)(Aph + (size_t)flat * 8 + 4) = h1;
    *(ushort4*)(Apl + (size_t)flat * 8)     = l0;
    *(ushort4*)(Apl + (size_t)flat * 8 + 4) = l1;
  }
}

// ---------------------------------------------------------------------------
// Kernel 3: partial shared projection via MFMA, D split 8 ways (was 4).
// Block (rowgrp, dq) = 16 rows x 512 k. Grid 4096 -> shorter barrier chain
// (2 staged chunks instead of 4) and more independent blocks per CU.
// fp32 path: x staged+split to swizzled LDS; bf16 path: direct loads.
// Output: fp32 partials, prepacked p[rowgrp][dq][lane][8].
// ---------------------------------------------------------------------------
__global__ __launch_bounds__(256) void k_sharedP(
    const void* __restrict__ xv, const void* __restrict__ Awv,
    const u16* __restrict__ Aph, const u16* __restrict__ Apl,
    float* __restrict__ pbuf) {
  __shared__ union {
    struct { u16 xh[4096]; u16 xl[4096]; } s;    // 16 KB staging
    float red4[4][512];                          // 8 KB reduce (after staging)
  } sm;
  int bf = detect_bf((const unsigned int*)xv);
  int t = threadIdx.x;
  int lane = t & 63;
  int wave = t >> 6;
  int m = lane & 15, kg = lane >> 4;
  int rowgrp = blockIdx.x >> 3;
  int dq = blockIdx.x & 7;                       // 0..7, 512 k each
  int row0 = rowgrp * 16;
  f32x4 acc0 = {0.f, 0.f, 0.f, 0.f};
  f32x4 acc1 = {0.f, 0.f, 0.f, 0.f};
  if (bf) {
    // wave owns contiguous 128-k strip of this block's 512-k range
    int kbase = dq * 512 + wave * 128 + kg * 8;
    const u16* xp = (const u16*)xv + (size_t)(row0 + m) * D_ + kbase;
    const u16* a0 = (const u16*)Awv + (size_t)m * D_ + kbase;
    const u16* a1 = (const u16*)Awv + (size_t)(m + 16) * D_ + kbase;
#pragma unroll
    for (int k0 = 0; k0 < 128; k0 += 32) {
      s16x8 a  = *(const s16x8*)(xp + k0);
      s16x8 b0 = *(const s16x8*)(a0 + k0);
      s16x8 b1 = *(const s16x8*)(a1 + k0);
      acc0 = __builtin_amdgcn_mfma_f32_16x16x32_bf16(a, b0, acc0, 0, 0, 0);
      acc1 = __builtin_amdgcn_mfma_f32_16x16x32_bf16(a, b1, acc1, 0, 0, 0);
    }
  } else {
    int srow = t >> 4;                   // staging row 0..15
    int sq = t & 15;                     // staging quad 0..15
    const float* xrow = (const float*)xv + (size_t)(row0 + srow) * D_ + dq * 512;
    for (int c = 0; c < 2; c++) {
      __syncthreads();                   // protect previous iter's reads
#pragma unroll
      for (int q = 0; q < 4; q++) {
        int colf = (sq + q * 16) * 4;    // float col within 256-chunk
        f32x4 v = *(const f32x4*)(xrow + c * 256 + colf);
        ushort4 h, l;
        split2(v[0], &h.x, &l.x); split2(v[1], &h.y, &l.y);
        split2(v[2], &h.z, &l.z); split2(v[3], &h.w, &l.w);
        // XOR on FULL byte address; identical formula on read side (rule 21)
        int swz = (srow * 512 + colf * 2) ^ ((srow & 7) << 4);
        *(ushort4*)((char*)sm.s.xh + swz) = h;
        *(ushort4*)((char*)sm.s.xl + swz) = l;
      }
      __syncthreads();
#pragma unroll
      for (int p2 = 0; p2 < 2; p2++) {
        int k32 = (wave * 2 + p2) * 32;  // this wave's k sub-chunk in [0,256)
        int boff = (m * 512 + (k32 + kg * 8) * 2) ^ ((m & 7) << 4);
        s16x8 ah = *(const s16x8*)((const char*)sm.s.xh + boff);
        s16x8 al = *(const s16x8*)((const char*)sm.s.xl + boff);
        int k32idx = dq * 16 + c * 8 + wave * 2 + p2;
        const u16* ph = Aph + (size_t)k32idx * 1024;  // [half][lane][8]
        const u16* pl = Apl + (size_t)k32idx * 1024;
        s16x8 bh0 = *(const s16x8*)(ph + (size_t)lane * 8);
        s16x8 bl0 = *(const s16x8*)(pl + (size_t)lane * 8);
        s16x8 bh1 = *(const s16x8*)(ph + 512 + (size_t)lane * 8);
        s16x8 bl1 = *(const s16x8*)(pl + 512 + (size_t)lane * 8);
        acc0 = __builtin_amdgcn_mfma_f32_16x16x32_bf16(ah, bh0, acc0, 0, 0, 0);
        acc0 = __builtin_amdgcn_mfma_f32_16x16x32_bf16(ah, bl0, acc0, 0, 0, 0);
        acc0 = __builtin_amdgcn_mfma_f32_16x16x32_bf16(al, bh0, acc0, 0, 0, 0);
        acc1 = __builtin_amdgcn_mfma_f32_16x16x32_bf16(ah, bh1, acc1, 0, 0, 0);
        acc1 = __builtin_amdgcn_mfma_f32_16x16x32_bf16(ah, bl1, acc1, 0, 0, 0);
        acc1 = __builtin_amdgcn_mfma_f32_16x16x32_bf16(al, bh1, acc1, 0, 0, 0);
      }
    }
  }
  __syncthreads();                       // staging reads done before red reuse
  // deposit wave partials: C layout col(r)=lane&15, row=(lane>>4)*4+j
  int crow = (lane >> 4) * 4, ccol = lane & 15;
#pragma unroll
  for (int j = 0; j < 4; j++) {
    sm.red4[wave][(crow + j) * 32 + ccol]      = acc0[j];
    sm.red4[wave][(crow + j) * 32 + ccol + 16] = acc1[j];
  }
  __syncthreads();
  // one wave reduces 4 planes and stores fp32 partials prepacked:
  // thread t = rq*16 + row owns sh[row][rq*8 .. rq*8+7] -> dst = t*8 + j
  if (t < 64) {
    int row = t & 15, rq = t >> 4;
    f32x4 va, vb;
#pragma unroll
    for (int j = 0; j < 4; j++) {
      int e = row * 32 + rq * 8 + j;
      va[j] = sm.red4[0][e] + sm.red4[1][e] + sm.red4[2][e] + sm.red4[3][e];
    }
#pragma unroll
    for (int j = 0; j < 4; j++) {
      int e = row * 32 + rq * 8 + 4 + j;
      vb[j] = sm.red4[0][e] + sm.red4[1][e] + sm.red4[2][e] + sm.red4[3][e];
    }
    float* pp = pbuf + ((size_t)rowgrp * 8 + dq) * 512 + t * 8;
    *(f32x4*)pp = va;
    *(f32x4*)(pp + 4) = vb;
  }
}

// ---------------------------------------------------------------------------
// Kernel 4: out[row, o] = sum_r sh[row, r] * Wc[b, o, r] via MFMA.
// Block (rowgrp, oq) = 16 rows x 512 o (o split 8 ways, was 4). Grid 4096.
// Sums 8 fp32 dq-partials in-register, splits to bf16 hi/lo fragments once,
// then 2 chunks of 256 o: 3-MFMA tiles -> LDS C [16][260] -> coalesced
// streaming stores (1 KB/wave-instr). Barrier chain halved.
// ---------------------------------------------------------------------------
__global__ __launch_bounds__(256) void k_outP(
    const void* __restrict__ xv, const float* __restrict__ pbuf,
    const u16* __restrict__ Wph, const u16* __restrict__ Wpl,
    void* __restrict__ out) {
  __shared__ float C[16][260];
  int bf = detect_bf((const unsigned int*)xv);
  int t = threadIdx.x;
  int lane = t & 63, wave = t >> 6, m = lane & 15;
  int rowgrp = blockIdx.x >> 3;
  int oq = blockIdx.x & 7;                      // 0..7, 512 o each
  int row0 = rowgrp * 16;
  int b = row0 >> 11;
  // reduce 8 dq-partials, build A fragments
  const float* pp = pbuf + (size_t)rowgrp * 8 * 512;
  f32x4 sa = {0.f, 0.f, 0.f, 0.f}, sb = {0.f, 0.f, 0.f, 0.f};
#pragma unroll
  for (int dq = 0; dq < 8; dq++) {
    sa += *(const f32x4*)(pp + dq * 512 + (size_t)lane * 8);
    sb += *(const f32x4*)(pp + dq * 512 + (size_t)lane * 8 + 4);
  }
  s16x8 Ah, Al;
  {
    u16 h, l;
#pragma unroll
    for (int j = 0; j < 4; j++) {
      split2(sa[j], &h, &l); Ah[j] = (short)h; Al[j] = (short)l;
      split2(sb[j], &h, &l); Ah[4 + j] = (short)h; Al[4 + j] = (short)l;
    }
  }
  int crow = (lane >> 4) * 4;
  const u16* whB = Wph + (size_t)b * 131072;   // 256 tiles * 512
  const u16* wlB = Wpl + (size_t)b * 131072;
  for (int cc = 0; cc < 2; cc++) {
    int tbase = oq * 32 + cc * 16;             // global tile base of chunk
#pragma unroll
    for (int i = 0; i < 4; i++) {
      int otc = wave * 4 + i;                  // tile within chunk 0..15
      size_t otg = (size_t)(tbase + otc);
      s16x8 Bh = *(const s16x8*)(whB + otg * 512 + (size_t)lane * 8);
      s16x8 Bl = *(const s16x8*)(wlB + otg * 512 + (size_t)lane * 8);
      f32x4 acc = {0.f, 0.f, 0.f, 0.f};
      acc = __builtin_amdgcn_mfma_f32_16x16x32_bf16(Ah, Bh, acc, 0, 0, 0);
      acc = __builtin_amdgcn_mfma_f32_16x16x32_bf16(Ah, Bl, acc, 0, 0, 0);
      acc = __builtin_amdgcn_mfma_f32_16x16x32_bf16(Al, Bh, acc, 0, 0, 0);
      int ocol = otc * 16 + m;
#pragma unroll
      for (int j = 0; j < 4; j++) C[crow + j][ocol] = acc[j];
    }
    __syncthreads();
    // stream 16 rows x 1 KB: 4 passes, 4 rows/pass, 1 KB contiguous/wave
#pragma unroll
    for (int pass = 0; pass < 4; pass++) {
      int row = pass * 4 + (t >> 6);
      int col = (t & 63) * 4;
      f32x4 v = *(const f32x4*)&C[row][col];
      size_t off = (size_t)(row0 + row) * O_ + oq * 512 + cc * 256 + col;
      if (bf) {
        ushort4 o4;
        o4.x = f2b(v[0]); o4.y = f2b(v[1]); o4.z = f2b(v[2]); o4.w = f2b(v[3]);
        *(ushort4*)((u16*)out + off) = o4;
      } else {
        *(f32x4*)((float*)out + off) = v;
      }
    }
    __syncthreads();                           // C reuse next chunk
  }
}

// ---------------------------------------------------------------------------
extern "C" void kernel_launch(void* const* d_in, const int* in_sizes, int n_in,
                              void* d_out, int out_size, void* d_ws, size_t ws_size,
                              hipStream_t stream) {
  const void* x       = d_in[0];                 // [4,2048,4096] f32 or bf16
  const int*  eof     = (const int*)d_in[1];     // [4]
  const void* noise   = d_in[2];                 // [4,8]
  const void* Aw      = d_in[3];                 // [32,4096]
  const void* Bw      = d_in[4];                 // [8,4096,32]
  const void* route_w = d_in[5];                 // [8,4096]
  const void* noise_w = d_in[6];                 // [8,4096]
  float* wsf = (float*)d_ws;
  // ws layout: [16,48) clean logits | [48,80) noise logits | then u16 planes
  u16* Wph  = (u16*)(wsf + 112);                 // 524288 u16 = 1 MB
  u16* Wpl  = Wph + (size_t)B_ * O_ * R_;        // 1 MB
  u16* Aph  = Wpl + (size_t)B_ * O_ * R_;        // 256 KB
  u16* Apl  = Aph + (size_t)R_ * D_;             // 256 KB
  float* pbuf = (float*)(Apl + (size_t)R_ * D_); // 512*8*512 f32 = 8 MB

  k_logits<<<B_ * E_, 256, 0, stream>>>(x, eof, route_w, noise_w, wsf);
  k_prep<<<512 + 64, 256, 0, stream>>>(Bw, (const float*)Aw, noise, x, wsf,
                                       Wph, Wpl, Aph, Apl);
  k_sharedP<<<4096, 256, 0, stream>>>(x, Aw, Aph, Apl, pbuf);
  k_outP<<<4096, 256, 0, stream>>>(x, pbuf, Wph, Wpl, d_out);
}